// Round 7
// baseline (415.364 us; speedup 1.0000x reference)
//
#include <hip/hip_runtime.h>
#include <stdint.h>

// Problem constants
#define kB  16384
#define kD  1024
#define kDE 512

typedef __bf16 bf16x8 __attribute__((ext_vector_type(8)));
typedef float  f32x4  __attribute__((ext_vector_type(4)));

__device__ __forceinline__ unsigned short f2bf(float f) {
    union { float f; unsigned u; } v; v.f = f;
    unsigned r = v.u + 0x7FFFu + ((v.u >> 16) & 1u);   // round-to-nearest-even
    return (unsigned short)(r >> 16);
}

__device__ __forceinline__ void async16(unsigned short* lds, const unsigned short* g) {
    __builtin_amdgcn_global_load_lds(
        (const __attribute__((address_space(1))) unsigned int*)g,
        (__attribute__((address_space(3))) unsigned int*)lds, 16, 0, 0);
}

// ------------- fused prep: weight transpose + x-convert + gate softmax -----
// blocks [0,1536): transpose/convert W -> Wt[slot][n][k] bf16
// blocks [1536,9728): x fp32->bf16 + gate softmax (one wave per row)
__global__ __launch_bounds__(256) void prep_all(
    const float* __restrict__ Wsh, const float* __restrict__ Wsp,
    unsigned short* __restrict__ Wt,
    const float* __restrict__ x0, const float* __restrict__ x1,
    const float* __restrict__ Wg, const float* __restrict__ bg,
    unsigned short* __restrict__ xb, float* __restrict__ g) {
    if (blockIdx.x < 1536) {
        __shared__ float tile[64][65];
        const int idx = blockIdx.x;
        const int slot = idx >> 7;
        const int rem = idx & 127;
        const int k0 = (rem & 15) * 64;
        const int n0 = (rem >> 4) * 64;
        const float* src = (slot < 4) ? (Wsh + (size_t)slot * kD * kDE)
                                      : (Wsp + (size_t)(slot - 4) * kD * kDE);
        const int tid = threadIdx.x;
        const int lr = tid >> 4, lc = (tid & 15) * 4;
#pragma unroll
        for (int i = 0; i < 4; i++) {
            const float4 v = *(const float4*)&src[(size_t)(k0 + lr + i * 16) * kDE + n0 + lc];
            tile[lr + i * 16][lc + 0] = v.x;
            tile[lr + i * 16][lc + 1] = v.y;
            tile[lr + i * 16][lc + 2] = v.z;
            tile[lr + i * 16][lc + 3] = v.w;
        }
        __syncthreads();
        const int wn = tid >> 2, wk = (tid & 3) * 16;
        unsigned short* dst = Wt + (size_t)slot * kDE * kD + (size_t)(n0 + wn) * kD + k0 + wk;
#pragma unroll
        for (int j = 0; j < 4; j++) {
            ushort4 h;
            h.x = f2bf(tile[wk + j * 4 + 0][wn]);
            h.y = f2bf(tile[wk + j * 4 + 1][wn]);
            h.z = f2bf(tile[wk + j * 4 + 2][wn]);
            h.w = f2bf(tile[wk + j * 4 + 3][wn]);
            *(ushort4*)(dst + j * 4) = h;
        }
        return;
    }
    const int wid = threadIdx.x >> 6, lane = threadIdx.x & 63;
    const int r = (blockIdx.x - 1536) * 4 + wid;
    const int t = r >> 14, b = r & 16383;
    const float* xrow = (t ? x1 : x0) + (size_t)b * kD;
    unsigned short* xbrow = xb + (size_t)(t * kB + b) * kD;
    const float* Wgt = Wg + t * kD * 8;
    float p[8] = {0.f,0.f,0.f,0.f,0.f,0.f,0.f,0.f};
#pragma unroll
    for (int it = 0; it < 4; it++) {
        const int d0 = it * 256 + lane * 4;
        const float4 v = *(const float4*)(xrow + d0);
        ushort4 h;
        h.x = f2bf(v.x); h.y = f2bf(v.y); h.z = f2bf(v.z); h.w = f2bf(v.w);
        *(ushort4*)(xbrow + d0) = h;
        const float xv[4] = {v.x, v.y, v.z, v.w};
#pragma unroll
        for (int j = 0; j < 4; j++) {
            const float* wrow = Wgt + (size_t)(d0 + j) * 8;
            const float4 wa = *(const float4*)wrow;
            const float4 wb = *(const float4*)(wrow + 4);
            p[0] += xv[j] * wa.x; p[1] += xv[j] * wa.y;
            p[2] += xv[j] * wa.z; p[3] += xv[j] * wa.w;
            p[4] += xv[j] * wb.x; p[5] += xv[j] * wb.y;
            p[6] += xv[j] * wb.z; p[7] += xv[j] * wb.w;
        }
    }
#pragma unroll
    for (int e = 0; e < 8; e++) {
        float v = p[e];
#pragma unroll
        for (int s = 1; s < 64; s <<= 1) v += __shfl_xor(v, s, 64);
        p[e] = v;
    }
    float lg[8];
#pragma unroll
    for (int e = 0; e < 8; e++) lg[e] = p[e] + bg[t * 8 + e];
    float mx = lg[0];
#pragma unroll
    for (int e = 1; e < 8; e++) mx = fmaxf(mx, lg[e]);
    float s = 0.f;
#pragma unroll
    for (int e = 0; e < 8; e++) { lg[e] = __expf(lg[e] - mx); s += lg[e]; }
    const float inv = 1.f / s;
    if (lane == 0) {
        float* gp = g + (size_t)(t * kB + b) * 8;
        float4 g0 = {lg[0]*inv, lg[1]*inv, lg[2]*inv, lg[3]*inv};
        float4 g1 = {lg[4]*inv, lg[5]*inv, lg[6]*inv, lg[7]*inv};
        *(float4*)gp = g0;
        *(float4*)(gp + 4) = g1;
    }
}

// --------------------------- fused MoE GEMM (4-phase/step interleave) ------
// Geometry unchanged from the proven kernel: M=128 x (8 experts x 64 cols),
// 8 waves, BK=64, dbuf. Per step: 4 phases, each {8 ds_reads pre-barrier ||
// 2-4 stage loads -> barrier -> lgkmcnt(0)+sched_barrier -> setprio(1) ->
// 16 MFMA -> setprio(0)}. Cross-wave staging deps handled by per-wave
// counted vmcnt + barrier: waves 0-3 stage A + own-expert B early (vmcnt(0)
// at step end), waves 4-7 stage A early / own B late (vmcnt(8) at step end,
// vmcnt(2) at next ph0 before the barrier preceding any ph1 read).
__global__ __launch_bounds__(512, 2) void moe_gemm(
    const unsigned short* __restrict__ xb, const unsigned short* __restrict__ Wt,
    const float* __restrict__ g, const float* __restrict__ bsh,
    const float* __restrict__ bsp, float* __restrict__ out) {
    __shared__ __align__(16) unsigned short As[2][128 * 64];      // 32 KB
    __shared__ __align__(16) unsigned short Bs[2][8 * 64 * 64];   // 128 KB

    // XCD-bijective swizzle (nwg=2048, %8==0)
    const int bid = blockIdx.x;
    const int swz = (bid & 7) * 256 + (bid >> 3);
    const int ct = swz & 7;
    const int rt = (swz >> 3) & 127;
    const int t  = swz >> 10;
    const int n0 = ct * 64;

    const int tid = threadIdx.x, wid = tid >> 6, lane = tid & 63;
    const int wr = wid >> 2, wc = wid & 3;
    const bool early = (wid < 4);

    // staging (pre-swizzled global source, linear LDS dest — rule #21)
    const int swzChunk = ((lane & 7) ^ ((lane >> 3) & 7)) * 8;
    const unsigned short* aSrc = xb + (size_t)t * kB * kD +
        (size_t)(rt * 128 + wid * 16 + (lane >> 3)) * kD + swzChunk;
    const int slot = (wid < 4) ? wid : (4 + t * 4 + (wid - 4));
    const unsigned short* bSrc = Wt + (size_t)slot * kDE * kD +
        (size_t)(n0 + (lane >> 3)) * kD + swzChunk;

    // fragment read offsets
    const int rAbase = (wr * 64 + (lane & 15)) * 64;
    const int bOff   = (wc * 16 + (lane & 15)) * 64;
    const int lx     = lane & 7;
    const int kg     = lane >> 4;

    f32x4 acc[8][4];
#pragma unroll
    for (int e = 0; e < 8; e++)
#pragma unroll
        for (int m = 0; m < 4; m++) acc[e][m] = (f32x4){0.f, 0.f, 0.f, 0.f};

    bf16x8 af[4], bfr[4];

#define S_A(buf, ktn)                                                          \
    async16(&As[buf][wid * 1024 + 0 * 512], aSrc + (ktn) * 64 + 0 * 8 * kD);   \
    async16(&As[buf][wid * 1024 + 1 * 512], aSrc + (ktn) * 64 + 1 * 8 * kD);

#define S_B(buf, ktn, j)                                                       \
    async16(&Bs[buf][wid * 4096 + (j) * 512], bSrc + (ktn) * 64 + (j) * 8 * kD);

#define R_A(buf, ks)                                                           \
    _Pragma("unroll")                                                          \
    for (int m = 0; m < 4; m++)                                                \
        af[m] = *(const bf16x8*)&As[buf][rAbase + m * 1024 +                   \
                                         ((((ks) * 4 + kg) ^ lx) << 3)];

#define R_B4(buf, ks, e0)                                                      \
    _Pragma("unroll")                                                          \
    for (int i = 0; i < 4; i++)                                                \
        bfr[i] = *(const bf16x8*)&Bs[buf][((e0) + i) * 4096 + bOff +           \
                                          ((((ks) * 4 + kg) ^ lx) << 3)];

#define MM4(e0)                                                                \
    asm volatile("s_waitcnt lgkmcnt(0)" ::: "memory");                         \
    __builtin_amdgcn_sched_barrier(0);                                         \
    __builtin_amdgcn_s_setprio(1);                                             \
    _Pragma("unroll")                                                          \
    for (int i = 0; i < 4; i++)                                                \
        _Pragma("unroll")                                                      \
        for (int m = 0; m < 4; m++)                                            \
            acc[(e0) + i][m] = __builtin_amdgcn_mfma_f32_16x16x32_bf16(        \
                af[m], bfr[i], acc[(e0) + i][m], 0, 0, 0);                     \
    __builtin_amdgcn_s_setprio(0);

#define STEP(cur, nxt, ktn)                                                    \
    {                                                                          \
        /* ph0: e0-3 ks0 */                                                    \
        R_A(cur, 0); R_B4(cur, 0, 0);                                          \
        if (early) {                                                           \
            S_A(nxt, ktn); S_B(nxt, ktn, 0); S_B(nxt, ktn, 1);                 \
        } else {                                                               \
            S_A(nxt, ktn);                                                     \
            asm volatile("s_waitcnt vmcnt(2)" ::: "memory");                   \
        }                                                                      \
        __builtin_amdgcn_s_barrier();                                          \
        MM4(0);                                                                \
        /* ph1: e4-7 ks0 (af reused) */                                        \
        R_B4(cur, 0, 4);                                                       \
        if (early) {                                                           \
            S_B(nxt, ktn, 2); S_B(nxt, ktn, 3);                                \
            S_B(nxt, ktn, 4); S_B(nxt, ktn, 5);                                \
        }                                                                      \
        __builtin_amdgcn_s_barrier();                                          \
        MM4(4);                                                                \
        /* ph2: e0-3 ks1 */                                                    \
        R_A(cur, 1); R_B4(cur, 1, 0);                                          \
        if (early) {                                                           \
            S_B(nxt, ktn, 6); S_B(nxt, ktn, 7);                                \
        } else {                                                               \
            S_B(nxt, ktn, 0); S_B(nxt, ktn, 1);                                \
            S_B(nxt, ktn, 2); S_B(nxt, ktn, 3);                                \
        }                                                                      \
        __builtin_amdgcn_s_barrier();                                          \
        MM4(0);                                                                \
        /* ph3: e4-7 ks1; then step-end guarantee for tile nxt */              \
        R_B4(cur, 1, 4);                                                       \
        if (!early) {                                                          \
            S_B(nxt, ktn, 4); S_B(nxt, ktn, 5);                                \
            S_B(nxt, ktn, 6); S_B(nxt, ktn, 7);                                \
        }                                                                      \
        __builtin_amdgcn_s_barrier();                                          \
        MM4(4);                                                                \
        if (early) { asm volatile("s_waitcnt vmcnt(0)" ::: "memory"); }        \
        else       { asm volatile("s_waitcnt vmcnt(8)" ::: "memory"); }        \
        __builtin_amdgcn_s_barrier();                                          \
    }

    // prologue: stage tile 0 into buf 0 (A first: oldest for vmcnt(8))
    S_A(0, 0);
    S_B(0, 0, 0); S_B(0, 0, 1); S_B(0, 0, 2); S_B(0, 0, 3);
    S_B(0, 0, 4); S_B(0, 0, 5); S_B(0, 0, 6); S_B(0, 0, 7);
    if (early) { asm volatile("s_waitcnt vmcnt(0)" ::: "memory"); }
    else       { asm volatile("s_waitcnt vmcnt(8)" ::: "memory"); }
    __builtin_amdgcn_s_barrier();

    for (int kt2 = 0; kt2 < 8; ++kt2) {
        STEP(0, 1, kt2 * 2 + 1)
        STEP(1, 0, (kt2 * 2 + 2) & 15)       // last iter restages tile 0 (benign)
    }
    asm volatile("s_waitcnt vmcnt(0)" ::: "memory");

#undef S_A
#undef S_B
#undef R_A
#undef R_B4
#undef MM4
#undef STEP

    // ---- epilogue: out = sum_e g_e * relu(acc[e] + bias_e), bias direct ----
    const int col = n0 + wc * 16 + (lane & 15);
    float bv[8];
#pragma unroll
    for (int e = 0; e < 8; e++)
        bv[e] = (e < 4) ? bsh[e * kDE + col] : bsp[(t * 4 + (e - 4)) * kDE + col];

#pragma unroll
    for (int m = 0; m < 4; m++) {
        const int r0 = rt * 128 + wr * 64 + m * 16 + kg * 4;
#pragma unroll
        for (int q = 0; q < 4; q++) {
            const float* gp = g + ((size_t)t * kB + r0 + q) * 8;
            const float4 ga = *(const float4*)gp;
            const float4 gb = *(const float4*)(gp + 4);
            float s = ga.x * fmaxf(acc[0][m][q] + bv[0], 0.f)
                    + ga.y * fmaxf(acc[1][m][q] + bv[1], 0.f)
                    + ga.z * fmaxf(acc[2][m][q] + bv[2], 0.f)
                    + ga.w * fmaxf(acc[3][m][q] + bv[3], 0.f)
                    + gb.x * fmaxf(acc[4][m][q] + bv[4], 0.f)
                    + gb.y * fmaxf(acc[5][m][q] + bv[5], 0.f)
                    + gb.z * fmaxf(acc[6][m][q] + bv[6], 0.f)
                    + gb.w * fmaxf(acc[7][m][q] + bv[7], 0.f);
            out[((size_t)(r0 + q) * 2 + t) * kDE + col] = s;
        }
    }
}

extern "C" void kernel_launch(void* const* d_in, const int* in_sizes, int n_in,
                              void* d_out, int out_size, void* d_ws, size_t ws_size,
                              hipStream_t stream) {
    const float* x0  = (const float*)d_in[0];
    const float* x1  = (const float*)d_in[1];
    const float* Wsh = (const float*)d_in[2];
    const float* bsh = (const float*)d_in[3];
    const float* Wsp = (const float*)d_in[4];
    const float* bsp = (const float*)d_in[5];
    const float* Wg  = (const float*)d_in[6];
    const float* bg  = (const float*)d_in[7];
    float* out = (float*)d_out;

    // ws layout (bytes): xb 67108864 | Wt 12582912 | g 1048576
    char* ws = (char*)d_ws;
    unsigned short* xb = (unsigned short*)ws;
    unsigned short* Wt = (unsigned short*)(ws + 67108864);
    float* g  = (float*)(ws + 67108864 + 12582912);

    prep_all<<<dim3(9728), dim3(256), 0, stream>>>(Wsh, Wsp, Wt, x0, x1, Wg, bg, xb, g);
    moe_gemm<<<dim3(2048), dim3(512), 0, stream>>>(xb, Wt, g, bsh, bsp, out);
}